// Round 15
// baseline (4515.894 us; speedup 1.0000x reference)
//
#include <hip/hip_runtime.h>
#include <hip/hip_fp16.h>
#include <cmath>

// ---------------------------------------------------------------------------
// LMU fused recurrence.  One 128x1536 @ 1536x1536 GEMM per step (tanh on
// first 1024 cols, linear on last 512), x-dependent rank-1 bias.
// r15 = r13 + hierarchical all-RMW island barrier.
//   r14 RCA: a plain `global_load ... sc0` does NOT bypass the CU L1 on
//   gfx950 -> pollers read a stale cached counter forever (absmax 0.13,
//   deadman spin-out).  LESSON: at workgroup scope the only reliable way to
//   observe a local-L2 counter is an atomic RMW (r13: passed, 3.95 ms).
//   r13 residual model: 32 poll-RMWs + arrivals on ONE L2 line saturate its
//   ~40cyc/RMW service port (queue ~1.3k cyc).  Fix: tree -- 4 leaf counters
//   (8 arrivals each) -> root (4 leaf leaders) -> 4 go words (7 pollers
//   each); max 8 RMWs contending per line, each counter in its own 256B
//   sector.  All arrivals AND polls are genuine RMWs (poll = inline-asm
//   global_atomic_add +0 sc0, immune to InstCombine per r12 RCA).
// Design (unchanged from r13):
//   - XCD-local islands (s_getreg XCC_ID + rank registration, 1 WG/CU).
//   - W_lo fully register-resident: 36 x half8 = 144 AGPRs/lane.
//   - W_hi slice (147 KB) in LDS; plain L2-local state loads/stores;
//     per-step CU-local L1 buffer_inv; busy spin, no s_sleep.
// Precision: EXACT r3-r13 verified scheme (absmax 4.9e-4): f16 hi/lo state
// and weights (lo x2048), fp32 MFMA accumulate, 3 products.
// ---------------------------------------------------------------------------

typedef _Float16 half8 __attribute__((ext_vector_type(8)));
typedef float floatx4 __attribute__((ext_vector_type(4)));

#define NSTATE   1536
#define BATCH    128
#define TSTEPS   784
#define KTILES   48
#define ISL_WGS  32                  // WGs per island (= CUs per XCD)
#define SLICE_H8 9216                // half8 per 48-col weight slice (48*3*64)
#define LO_SCALE 2048.0f
#define LO_INV   (1.0f / 2048.0f)

__device__ __align__(16) _Float16 g_Whi[NSTATE * NSTATE];
__device__ __align__(16) _Float16 g_Wlo[NSTATE * NSTATE];
__device__ float    g_wb[NSTATE];
__device__ float    g_WmA[1024 * 512];
__device__ float    g_WmB[1024];
__device__ __align__(16) _Float16 g_Shi[2 * BATCH * NSTATE];
__device__ __align__(16) _Float16 g_Slo[2 * BATCH * NSTATE];
// Layout (one 256B sector per counter):
//   isl*576 + j*64          : leaf arrival counters, j=0..3
//   isl*576 + 4*64          : root counter
//   isl*576 + (5+j)*64      : go words, j=0..3
//   7680 + isl*64           : registration counters
__device__ unsigned g_bar[8192];

// Forced local-L2 atomic RMW poll (returns pre-add value).  InstCombine
// cannot demote this to a (stale-L1-cacheable) load -- r12/r14 lessons.
__device__ __forceinline__ unsigned poll_rmw(unsigned* p) {
    unsigned old;
    asm volatile("global_atomic_add %0, %1, %2, off sc0\n\ts_waitcnt vmcnt(0)"
                 : "=&v"(old)
                 : "v"(p), "v"(0u)
                 : "memory");
    return old;
}

// W_mB[i] = sum_c W_m[i,c] * BT[c]
__global__ void prep_wmb(const float* __restrict__ Wm, const float* __restrict__ BT) {
    int row  = blockIdx.x * 4 + (threadIdx.x >> 6);
    int lane = threadIdx.x & 63;
    float s = 0.f;
    for (int c = lane; c < 512; c += 64) s += Wm[row * 512 + c] * BT[c];
    for (int o = 32; o; o >>= 1) s += __shfl_down(s, o);
    if (lane == 0) g_WmB[row] = s;
}

// W_mA = W_m @ (I + AT)
__global__ void prep_wma(const float* __restrict__ Wm, const float* __restrict__ AT) {
    __shared__ float As[32][33], Bs[32][33];
    int d0 = blockIdx.x * 32, i0 = blockIdx.y * 32;
    int tx = threadIdx.x & 31, ty = threadIdx.x >> 5;
    float acc[4];
#pragma unroll
    for (int r = 0; r < 4; ++r) acc[r] = Wm[(i0 + ty + 8 * r) * 512 + d0 + tx];
    for (int c0 = 0; c0 < 512; c0 += 32) {
#pragma unroll
        for (int r = 0; r < 4; ++r) {
            As[ty + 8 * r][tx] = Wm[(i0 + ty + 8 * r) * 512 + c0 + tx];
            Bs[ty + 8 * r][tx] = AT[(c0 + ty + 8 * r) * 512 + d0 + tx];
        }
        __syncthreads();
#pragma unroll
        for (int c = 0; c < 32; ++c)
#pragma unroll
            for (int r = 0; r < 4; ++r) acc[r] += As[ty + 8 * r][c] * Bs[c][tx];
        __syncthreads();
    }
#pragma unroll
    for (int r = 0; r < 4; ++r) g_WmA[(i0 + ty + 8 * r) * 512 + d0 + tx] = acc[r];
}

// Build W_full, f16 hi/lo (lo x2048), in slice-major fragment order:
// storage s = (((sl*48 + kt)*3 + nt)*64 + lane)*8 + j
//   n = sl*48 + nt*16 + (lane&15),  k = kt*32 + ((lane>>4)&3)*8 + j
__global__ void prep_wfull(const float* __restrict__ Wh, const float* __restrict__ AT,
                           const float* __restrict__ BT, const float* __restrict__ eh,
                           const float* __restrict__ em, const float* __restrict__ ex,
                           const float* __restrict__ Wx) {
    int s = blockIdx.x * 256 + threadIdx.x;     // [0, 1536*1536)
    int j8 = s & 7;
    int u = s >> 3;
    int lane = u & 63;
    u >>= 6;                                    // [0, 4608)
    int nt = u % 3; u /= 3;
    int kt = u % 48;
    int sl = u / 48;
    int n = sl * 48 + nt * 16 + (lane & 15);
    int k = kt * 32 + ((lane >> 4) & 3) * 8 + j8;

    float w;
    if (n < 1024) {
        if (k < 1024) w = Wh[n * 1024 + k] + g_WmB[n] * eh[k];
        else          w = g_WmA[n * 512 + (k - 1024)] + g_WmB[n] * em[k - 1024];
    } else {
        int c = n - 1024;
        if (k < 1024) w = BT[c] * eh[k];
        else {
            int d = k - 1024;
            w = ((c == d) ? 1.f : 0.f) + AT[c * 512 + d] + BT[c] * em[d];
        }
    }
    _Float16 hi = (_Float16)w;
    g_Whi[s] = hi;
    g_Wlo[s] = (_Float16)((w - (float)hi) * LO_SCALE);

    if (s < NSTATE) {
        float b = (s < 1024) ? (Wx[s] + ex[0] * g_WmB[s]) : (BT[s - 1024] * ex[0]);
        g_wb[s] = b;
    }
    if (s < 2 * BATCH * NSTATE) { g_Shi[s] = (_Float16)0.f; g_Slo[s] = (_Float16)0.f; }
    if (s < 8192) g_bar[s] = 0u;
}

__launch_bounds__(256, 1)
__global__ void lmu_persist(const float* __restrict__ inputs) {
    __shared__ half8  lwh[SLICE_H8];            // 147456 B: W_hi slice
    __shared__ float4 red[4 * 3 * 64];          // 12288 B: K-split partials
    __shared__ int    s_sl;

    const int tid = threadIdx.x;

    // ---- physical XCD id + rank registration (island = XCD; rank == sl) ----
    unsigned xcd;
    asm volatile("s_getreg_b32 %0, hwreg(HW_REG_XCC_ID)" : "=s"(xcd));
    xcd &= 7u;
    if (tid == 0) {
        unsigned rank = __hip_atomic_fetch_add(g_bar + 7680 + xcd * 64, 1u,
                                               __ATOMIC_RELAXED,
                                               __HIP_MEMORY_SCOPE_WORKGROUP);
        s_sl = (int)(rank & 31u);               // column slice [0,32)
    }
    __syncthreads();
    const int isl = (int)xcd;                   // batch rows isl*16..+16
    const int sl  = s_sl;                       // cols sl*48..+48

    // stage W_hi slice -> LDS
    {
        const half8* src = (const half8*)g_Whi + (size_t)sl * SLICE_H8;
        for (int i = tid; i < SLICE_H8; i += 256) lwh[i] = src[i];
    }

    const int lane = tid & 63, wv = tid >> 6;
    const int quad = lane >> 4, l16 = lane & 15;
    const int kt0 = wv * 12;                    // this wave's K range
    const int rowA = isl * 16 + l16;            // A-frag batch row

    // tree-barrier pointers (each in its own 256B sector of the local L2)
    unsigned* const base = g_bar + isl * 576;
    unsigned* const leaf = base + (sl >> 3) * 64;
    unsigned* const root = base + 4 * 64;
    unsigned* const go   = base + (5 + (sl >> 3)) * 64;
    const bool leafldr = (sl & 7) == 0;

    // epilogue constants (wave wv<3 handles nt=wv)
    const int ncol = sl * 48 + wv * 16 + l16;
    const float wbv = (wv < 3) ? g_wb[ncol] : 0.f;
    const bool do_tanh = (sl * 48 + wv * 16) < 1024;

    // ---- W_lo: FULLY register-resident (36 x half8 = 144 AGPRs), loaded once
    half8 wr[12 * 3];
    {
        const half8* wlo = (const half8*)g_Wlo + (size_t)sl * SLICE_H8;
#pragma unroll
        for (int ki = 0; ki < 12; ++ki)
#pragma unroll
            for (int nt = 0; nt < 3; ++nt)
                wr[ki * 3 + nt] = wlo[((kt0 + ki) * 3 + nt) * 64 + lane];
    }

    __syncthreads();

    int buf = 0;
    for (int t = 0; t < TSTEPS; ++t) {
        // PLAIN loads: producers share this XCD's L2 -> L2-local traffic
        const _Float16* shr =
            g_Shi + buf * BATCH * NSTATE + rowA * NSTATE + quad * 8;
        const _Float16* slr =
            g_Slo + buf * BATCH * NSTATE + rowA * NSTATE + quad * 8;

        floatx4 aA[3], aB[3], aC[3];
#pragma unroll
        for (int q = 0; q < 3; ++q) { aA[q] = (floatx4)0.f; aB[q] = (floatx4)0.f; aC[q] = (floatx4)0.f; }

#pragma unroll
        for (int ki = 0; ki < 12; ++ki) {
            const int kt = kt0 + ki;
            half8 ah = *(const half8*)(shr + kt * 32);
            half8 al = *(const half8*)(slr + kt * 32);
#pragma unroll
            for (int nt = 0; nt < 3; ++nt) {
                half8 bh = lwh[(kt * 3 + nt) * 64 + lane];
                aA[nt] = __builtin_amdgcn_mfma_f32_16x16x32_f16(ah, bh, aA[nt], 0, 0, 0);
                aB[nt] = __builtin_amdgcn_mfma_f32_16x16x32_f16(al, bh, aB[nt], 0, 0, 0);
                aC[nt] = __builtin_amdgcn_mfma_f32_16x16x32_f16(ah, wr[ki * 3 + nt], aC[nt], 0, 0, 0);
            }
        }

        // K-split partials -> LDS
#pragma unroll
        for (int nt = 0; nt < 3; ++nt) {
            floatx4 P = aA[nt] + (aB[nt] + aC[nt]) * LO_INV;
            red[(wv * 3 + nt) * 64 + lane] = float4{P[0], P[1], P[2], P[3]};
        }
        __syncthreads();

        // waves 0-2: reduce + bias + activation + hi/lo split + PLAIN store
        const int nbuf = buf ^ 1;
        if (wv < 3) {
            float4 v0 = red[(0 * 3 + wv) * 64 + lane];
            float4 v1 = red[(1 * 3 + wv) * 64 + lane];
            float4 v2 = red[(2 * 3 + wv) * 64 + lane];
            float4 v3 = red[(3 * 3 + wv) * 64 + lane];
            float vr4[4] = {v0.x + v1.x + v2.x + v3.x, v0.y + v1.y + v2.y + v3.y,
                            v0.z + v1.z + v2.z + v3.z, v0.w + v1.w + v2.w + v3.w};
            _Float16* dh = g_Shi + nbuf * BATCH * NSTATE;
            _Float16* dl = g_Slo + nbuf * BATCH * NSTATE;
            const float* xt = inputs + t * BATCH + isl * 16 + quad * 4;
#pragma unroll
            for (int r = 0; r < 4; ++r) {
                int b = isl * 16 + quad * 4 + r;
                float v = vr4[r] + xt[r] * wbv;
                if (do_tanh) v = tanhf(v);
                _Float16 hi = (_Float16)v;
                dh[b * NSTATE + ncol] = hi;
                dl[b * NSTATE + ncol] = (_Float16)((v - (float)hi) * LO_SCALE);
            }
        }

        // drain stores (syncthreads emits vmcnt(0)), then TREE barrier in the
        // local L2: leaf(8 arrivals) -> root(4 leaders) -> go(7 pollers/leaf).
        __builtin_amdgcn_fence(__ATOMIC_RELEASE, "workgroup");
        __syncthreads();
        if (tid == 0) {
            const unsigned t1 = (unsigned)(t + 1);
            __hip_atomic_fetch_add(leaf, 1u, __ATOMIC_RELAXED,
                                   __HIP_MEMORY_SCOPE_WORKGROUP);
            int spin = 0;
            if (leafldr) {
                while (poll_rmw(leaf) < 8u * t1) {          // my 7 members
                    if (++spin > (1 << 18)) break;
                }
                __hip_atomic_fetch_add(root, 1u, __ATOMIC_RELAXED,
                                       __HIP_MEMORY_SCOPE_WORKGROUP);
                spin = 0;
                while (poll_rmw(root) < 4u * t1) {          // other 3 leaders
                    if (++spin > (1 << 18)) break;
                }
                __hip_atomic_fetch_add(go, 1u, __ATOMIC_RELAXED,
                                       __HIP_MEMORY_SCOPE_WORKGROUP);
            } else {
                while (poll_rmw(go) < t1) {
                    if (++spin > (1 << 18)) break;
                }
            }
        }
        __syncthreads();
        // CU-local L1 invalidate only (L2 holds the island's fresh state)
        asm volatile("buffer_inv\n\ts_waitcnt vmcnt(0)" ::: "memory");
        __builtin_amdgcn_fence(__ATOMIC_ACQUIRE, "workgroup");
        buf = nbuf;
    }
}

// logits + softmax: one WG per batch row (final state in plane 0: 784 even;
// dispatch boundary flushes every XCD's L2 so state is globally visible).
__global__ void lmu_out(const float* __restrict__ Wd, const float* __restrict__ bd,
                        float* __restrict__ out) {
    __shared__ float red[272];
    int b = blockIdx.x;
    const _Float16* sh = g_Shi + b * NSTATE;
    const _Float16* sl = g_Slo + b * NSTATE;
    int tid = threadIdx.x;
    int c = tid & 15, chunk = tid >> 4;
    float part = 0.f;
    if (c < 10) {
        for (int i = chunk * 64; i < chunk * 64 + 64; ++i)
            part += ((float)sh[i] + (float)sl[i] * LO_INV) * Wd[c * 1024 + i];
    }
    red[chunk * 16 + c] = part;
    __syncthreads();
    if (tid < 10) {
        float lg = bd[tid];
        for (int q = 0; q < 16; ++q) lg += red[q * 16 + tid];
        red[256 + tid] = lg;
    }
    __syncthreads();
    if (tid < 10) {
        float mx = red[256];
        for (int q = 1; q < 10; ++q) mx = fmaxf(mx, red[256 + q]);
        float sm = 0.f;
        for (int q = 0; q < 10; ++q) sm += expf(red[256 + q] - mx);
        out[b * 10 + tid] = expf(red[256 + tid] - mx) / sm;
    }
}

extern "C" void kernel_launch(void* const* d_in, const int* in_sizes, int n_in,
                              void* d_out, int out_size, void* d_ws, size_t ws_size,
                              hipStream_t stream) {
    const float* inputs = (const float*)d_in[0];
    const float* e_x    = (const float*)d_in[1];
    const float* e_h    = (const float*)d_in[2];
    const float* e_m    = (const float*)d_in[3];
    const float* W_x    = (const float*)d_in[4];
    const float* W_h    = (const float*)d_in[5];
    const float* W_m    = (const float*)d_in[6];
    const float* AT     = (const float*)d_in[7];
    const float* BT     = (const float*)d_in[8];
    const float* W_d    = (const float*)d_in[9];
    const float* b_d    = (const float*)d_in[10];
    (void)d_ws; (void)ws_size; (void)in_sizes; (void)n_in;

    prep_wmb<<<256, 256, 0, stream>>>(W_m, BT);
    prep_wma<<<dim3(16, 32), 256, 0, stream>>>(W_m, AT);
    prep_wfull<<<9216, 256, 0, stream>>>(W_h, AT, BT, e_h, e_m, e_x, W_x);

    lmu_persist<<<256, 256, 0, stream>>>(inputs);

    lmu_out<<<128, 256, 0, stream>>>(W_d, b_d, (float*)d_out);
}

// Round 17
// 4142.144 us; speedup vs baseline: 1.0902x; 1.0902x over previous
//
#include <hip/hip_runtime.h>
#include <hip/hip_fp16.h>
#include <cmath>

// ---------------------------------------------------------------------------
// LMU fused recurrence.  One 128x1536 @ 1536x1536 GEMM per step (tanh on
// first 1024 cols, linear on last 512), x-dependent rank-1 bias.
// r17 = r13 + ALL-RMW low-contention barrier.
//   r16 RCA: mixed plain stores with RMW(+0) polls on the same word -- an
//   RMW's write-back can clobber a store landing between its read and write
//   phases (store path vs atomic path in the TCC race) -> arrival lost ->
//   deadman -> silent replay divergence.  RULE: barrier words are touched by
//   atomic RMWs ONLY (r13, all-fetch_add, was replay-stable).
//   Structure: per-WG arrival counter (fetch_add +1/step, own 256B sector);
//   leader WG wave-0 lanes RMW(+0)-poll all 32 flags IN PARALLEL (1 arriver
//   + 1 poller per line), ballot, then fetch_add(+1) 32 private go counters
//   in one instruction; members RMW(+0)-poll their own go counter.
//   Critical path ~1.0k cyc vs r13's saturated single-line ~1.5-1.8k.
//   buffer_inv (CU L1) BEFORE the wait: polls are RMWs (bypass L1), no
//   vector loads until after go -> inv latency hides behind the wait.
// Design (unchanged from r13):
//   - XCD-local islands (s_getreg XCC_ID + rank registration, 1 WG/CU).
//   - W_lo fully register-resident: 36 x half8 = 144 AGPRs/lane.
//   - W_hi slice (147 KB) in LDS; plain L2-local state loads/stores.
// Precision: EXACT r3-r13 verified scheme (absmax 4.9e-4): f16 hi/lo state
// and weights (lo x2048), fp32 MFMA accumulate, 3 products.
// ---------------------------------------------------------------------------

typedef _Float16 half8 __attribute__((ext_vector_type(8)));
typedef float floatx4 __attribute__((ext_vector_type(4)));

#define NSTATE   1536
#define BATCH    128
#define TSTEPS   784
#define KTILES   48
#define ISL_WGS  32                  // WGs per island (= CUs per XCD)
#define SLICE_H8 9216                // half8 per 48-col weight slice (48*3*64)
#define LO_SCALE 2048.0f
#define LO_INV   (1.0f / 2048.0f)

__device__ __align__(16) _Float16 g_Whi[NSTATE * NSTATE];
__device__ __align__(16) _Float16 g_Wlo[NSTATE * NSTATE];
__device__ float    g_wb[NSTATE];
__device__ float    g_WmA[1024 * 512];
__device__ float    g_WmB[1024];
__device__ __align__(16) _Float16 g_Shi[2 * BATCH * NSTATE];
__device__ __align__(16) _Float16 g_Slo[2 * BATCH * NSTATE];
// Layout (one 256B sector = 64 words per counter; RMW-only access):
//   isl*4096 + sl*64        : arrival counters (value = steps completed)
//   isl*4096 + (32+sl)*64   : go counters     (value = steps released)
//   32768 + isl*64          : registration counters
__device__ unsigned g_bar[33280];

// Forced local-L2 atomic RMW poll (returns pre-add value).  InstCombine
// cannot demote this to a (stale-L1-cacheable) load -- r12/r14 lessons.
__device__ __forceinline__ unsigned poll_rmw(unsigned* p) {
    unsigned old;
    asm volatile("global_atomic_add %0, %1, %2, off sc0\n\ts_waitcnt vmcnt(0)"
                 : "=&v"(old)
                 : "v"(p), "v"(0u)
                 : "memory");
    return old;
}

// W_mB[i] = sum_c W_m[i,c] * BT[c]
__global__ void prep_wmb(const float* __restrict__ Wm, const float* __restrict__ BT) {
    int row  = blockIdx.x * 4 + (threadIdx.x >> 6);
    int lane = threadIdx.x & 63;
    float s = 0.f;
    for (int c = lane; c < 512; c += 64) s += Wm[row * 512 + c] * BT[c];
    for (int o = 32; o; o >>= 1) s += __shfl_down(s, o);
    if (lane == 0) g_WmB[row] = s;
}

// W_mA = W_m @ (I + AT)
__global__ void prep_wma(const float* __restrict__ Wm, const float* __restrict__ AT) {
    __shared__ float As[32][33], Bs[32][33];
    int d0 = blockIdx.x * 32, i0 = blockIdx.y * 32;
    int tx = threadIdx.x & 31, ty = threadIdx.x >> 5;
    float acc[4];
#pragma unroll
    for (int r = 0; r < 4; ++r) acc[r] = Wm[(i0 + ty + 8 * r) * 512 + d0 + tx];
    for (int c0 = 0; c0 < 512; c0 += 32) {
#pragma unroll
        for (int r = 0; r < 4; ++r) {
            As[ty + 8 * r][tx] = Wm[(i0 + ty + 8 * r) * 512 + c0 + tx];
            Bs[ty + 8 * r][tx] = AT[(c0 + ty + 8 * r) * 512 + d0 + tx];
        }
        __syncthreads();
#pragma unroll
        for (int c = 0; c < 32; ++c)
#pragma unroll
            for (int r = 0; r < 4; ++r) acc[r] += As[ty + 8 * r][c] * Bs[c][tx];
        __syncthreads();
    }
#pragma unroll
    for (int r = 0; r < 4; ++r) g_WmA[(i0 + ty + 8 * r) * 512 + d0 + tx] = acc[r];
}

// Build W_full, f16 hi/lo (lo x2048), in slice-major fragment order:
// storage s = (((sl*48 + kt)*3 + nt)*64 + lane)*8 + j
//   n = sl*48 + nt*16 + (lane&15),  k = kt*32 + ((lane>>4)&3)*8 + j
__global__ void prep_wfull(const float* __restrict__ Wh, const float* __restrict__ AT,
                           const float* __restrict__ BT, const float* __restrict__ eh,
                           const float* __restrict__ em, const float* __restrict__ ex,
                           const float* __restrict__ Wx) {
    int s = blockIdx.x * 256 + threadIdx.x;     // [0, 1536*1536)
    int j8 = s & 7;
    int u = s >> 3;
    int lane = u & 63;
    u >>= 6;                                    // [0, 4608)
    int nt = u % 3; u /= 3;
    int kt = u % 48;
    int sl = u / 48;
    int n = sl * 48 + nt * 16 + (lane & 15);
    int k = kt * 32 + ((lane >> 4) & 3) * 8 + j8;

    float w;
    if (n < 1024) {
        if (k < 1024) w = Wh[n * 1024 + k] + g_WmB[n] * eh[k];
        else          w = g_WmA[n * 512 + (k - 1024)] + g_WmB[n] * em[k - 1024];
    } else {
        int c = n - 1024;
        if (k < 1024) w = BT[c] * eh[k];
        else {
            int d = k - 1024;
            w = ((c == d) ? 1.f : 0.f) + AT[c * 512 + d] + BT[c] * em[d];
        }
    }
    _Float16 hi = (_Float16)w;
    g_Whi[s] = hi;
    g_Wlo[s] = (_Float16)((w - (float)hi) * LO_SCALE);

    if (s < NSTATE) {
        float b = (s < 1024) ? (Wx[s] + ex[0] * g_WmB[s]) : (BT[s - 1024] * ex[0]);
        g_wb[s] = b;
    }
    if (s < 2 * BATCH * NSTATE) { g_Shi[s] = (_Float16)0.f; g_Slo[s] = (_Float16)0.f; }
    if (s < 33280) g_bar[s] = 0u;
}

__launch_bounds__(256, 1)
__global__ void lmu_persist(const float* __restrict__ inputs) {
    __shared__ half8  lwh[SLICE_H8];            // 147456 B: W_hi slice
    __shared__ float4 red[4 * 3 * 64];          // 12288 B: K-split partials
    __shared__ int    s_sl;

    const int tid = threadIdx.x;

    // ---- physical XCD id + rank registration (island = XCD; rank == sl) ----
    unsigned xcd;
    asm volatile("s_getreg_b32 %0, hwreg(HW_REG_XCC_ID)" : "=s"(xcd));
    xcd &= 7u;
    if (tid == 0) {
        unsigned rank = __hip_atomic_fetch_add(g_bar + 32768 + xcd * 64, 1u,
                                               __ATOMIC_RELAXED,
                                               __HIP_MEMORY_SCOPE_WORKGROUP);
        s_sl = (int)(rank & 31u);               // column slice [0,32)
    }
    __syncthreads();
    const int isl = (int)xcd;                   // batch rows isl*16..+16
    const int sl  = s_sl;                       // cols sl*48..+48

    // stage W_hi slice -> LDS
    {
        const half8* src = (const half8*)g_Whi + (size_t)sl * SLICE_H8;
        for (int i = tid; i < SLICE_H8; i += 256) lwh[i] = src[i];
    }

    const int lane = tid & 63, wv = tid >> 6;
    const int quad = lane >> 4, l16 = lane & 15;
    const int kt0 = wv * 12;                    // this wave's K range
    const int rowA = isl * 16 + l16;            // A-frag batch row

    // barrier pointers (each counter in its own 256B sector of the local L2)
    unsigned* const flagbase = g_bar + isl * 4096;
    unsigned* const myflag   = flagbase + sl * 64;
    unsigned* const mygo     = flagbase + (32 + sl) * 64;
    const bool leaderWG = (sl == 0);

    // epilogue constants (wave wv<3 handles nt=wv)
    const int ncol = sl * 48 + wv * 16 + l16;
    const float wbv = (wv < 3) ? g_wb[ncol] : 0.f;
    const bool do_tanh = (sl * 48 + wv * 16) < 1024;

    // ---- W_lo: FULLY register-resident (36 x half8 = 144 AGPRs), loaded once
    half8 wr[12 * 3];
    {
        const half8* wlo = (const half8*)g_Wlo + (size_t)sl * SLICE_H8;
#pragma unroll
        for (int ki = 0; ki < 12; ++ki)
#pragma unroll
            for (int nt = 0; nt < 3; ++nt)
                wr[ki * 3 + nt] = wlo[((kt0 + ki) * 3 + nt) * 64 + lane];
    }

    __syncthreads();

    int buf = 0;
    for (int t = 0; t < TSTEPS; ++t) {
        // PLAIN loads: producers share this XCD's L2 -> L2-local traffic
        const _Float16* shr =
            g_Shi + buf * BATCH * NSTATE + rowA * NSTATE + quad * 8;
        const _Float16* slr =
            g_Slo + buf * BATCH * NSTATE + rowA * NSTATE + quad * 8;

        floatx4 aA[3], aB[3], aC[3];
#pragma unroll
        for (int q = 0; q < 3; ++q) { aA[q] = (floatx4)0.f; aB[q] = (floatx4)0.f; aC[q] = (floatx4)0.f; }

#pragma unroll
        for (int ki = 0; ki < 12; ++ki) {
            const int kt = kt0 + ki;
            half8 ah = *(const half8*)(shr + kt * 32);
            half8 al = *(const half8*)(slr + kt * 32);
#pragma unroll
            for (int nt = 0; nt < 3; ++nt) {
                half8 bh = lwh[(kt * 3 + nt) * 64 + lane];
                aA[nt] = __builtin_amdgcn_mfma_f32_16x16x32_f16(ah, bh, aA[nt], 0, 0, 0);
                aB[nt] = __builtin_amdgcn_mfma_f32_16x16x32_f16(al, bh, aB[nt], 0, 0, 0);
                aC[nt] = __builtin_amdgcn_mfma_f32_16x16x32_f16(ah, wr[ki * 3 + nt], aC[nt], 0, 0, 0);
            }
        }

        // K-split partials -> LDS
#pragma unroll
        for (int nt = 0; nt < 3; ++nt) {
            floatx4 P = aA[nt] + (aB[nt] + aC[nt]) * LO_INV;
            red[(wv * 3 + nt) * 64 + lane] = float4{P[0], P[1], P[2], P[3]};
        }
        __syncthreads();

        // waves 0-2: reduce + bias + activation + hi/lo split + PLAIN store
        const int nbuf = buf ^ 1;
        if (wv < 3) {
            float4 v0 = red[(0 * 3 + wv) * 64 + lane];
            float4 v1 = red[(1 * 3 + wv) * 64 + lane];
            float4 v2 = red[(2 * 3 + wv) * 64 + lane];
            float4 v3 = red[(3 * 3 + wv) * 64 + lane];
            float vr4[4] = {v0.x + v1.x + v2.x + v3.x, v0.y + v1.y + v2.y + v3.y,
                            v0.z + v1.z + v2.z + v3.z, v0.w + v1.w + v2.w + v3.w};
            _Float16* dh = g_Shi + nbuf * BATCH * NSTATE;
            _Float16* dl = g_Slo + nbuf * BATCH * NSTATE;
            const float* xt = inputs + t * BATCH + isl * 16 + quad * 4;
#pragma unroll
            for (int r = 0; r < 4; ++r) {
                int b = isl * 16 + quad * 4 + r;
                float v = vr4[r] + xt[r] * wbv;
                if (do_tanh) v = tanhf(v);
                _Float16 hi = (_Float16)v;
                dh[b * NSTATE + ncol] = hi;
                dl[b * NSTATE + ncol] = (_Float16)((v - (float)hi) * LO_SCALE);
            }
        }

        // ---- barrier: RMW-arrive / parallel RMW-sweep / private RMW-go ----
        const unsigned t1 = (unsigned)(t + 1);
        __builtin_amdgcn_fence(__ATOMIC_RELEASE, "workgroup");
        __syncthreads();                        // all WG stores at L2 (vmcnt 0)
        // CU-local L1 inv before the wait: polls are RMWs (bypass L1), no
        // vector loads until after go -> inv latency hides behind the wait.
        asm volatile("buffer_inv\n\ts_waitcnt vmcnt(0)" ::: "memory");
        if (tid == 0)
            __hip_atomic_fetch_add(myflag, 1u, __ATOMIC_RELAXED,
                                   __HIP_MEMORY_SCOPE_WORKGROUP);
        if (leaderWG) {
            if (wv == 0) {
                // 32 lanes poll all arrival counters in parallel (1 arriver
                // + 1 poller per 256B sector; all accesses are atomic RMWs)
                unsigned* fp = flagbase + (lane & 31) * 64;
                int spin = 0;
                for (;;) {
                    unsigned v = (lane < 32) ? poll_rmw(fp) : t1;
                    if (__ballot(v >= t1) == ~0ULL) break;
                    if (++spin > (1 << 18)) break;          // deadman
                }
                if (lane < 32)
                    __hip_atomic_fetch_add(flagbase + (32 + lane) * 64, 1u,
                                           __ATOMIC_RELAXED,
                                           __HIP_MEMORY_SCOPE_WORKGROUP);
            }
        } else if (tid == 0) {
            int spin = 0;
            while (poll_rmw(mygo) < t1) {       // own sector: zero contention
                if (++spin > (1 << 18)) break;  // deadman
            }
        }
        __syncthreads();
        __builtin_amdgcn_fence(__ATOMIC_ACQUIRE, "workgroup");
        buf = nbuf;
    }
}

// logits + softmax: one WG per batch row (final state in plane 0: 784 even;
// dispatch boundary flushes every XCD's L2 so state is globally visible).
__global__ void lmu_out(const float* __restrict__ Wd, const float* __restrict__ bd,
                        float* __restrict__ out) {
    __shared__ float red[272];
    int b = blockIdx.x;
    const _Float16* sh = g_Shi + b * NSTATE;
    const _Float16* sl = g_Slo + b * NSTATE;
    int tid = threadIdx.x;
    int c = tid & 15, chunk = tid >> 4;
    float part = 0.f;
    if (c < 10) {
        for (int i = chunk * 64; i < chunk * 64 + 64; ++i)
            part += ((float)sh[i] + (float)sl[i] * LO_INV) * Wd[c * 1024 + i];
    }
    red[chunk * 16 + c] = part;
    __syncthreads();
    if (tid < 10) {
        float lg = bd[tid];
        for (int q = 0; q < 16; ++q) lg += red[q * 16 + tid];
        red[256 + tid] = lg;
    }
    __syncthreads();
    if (tid < 10) {
        float mx = red[256];
        for (int q = 1; q < 10; ++q) mx = fmaxf(mx, red[256 + q]);
        float sm = 0.f;
        for (int q = 0; q < 10; ++q) sm += expf(red[256 + q] - mx);
        out[b * 10 + tid] = expf(red[256 + tid] - mx) / sm;
    }
}

extern "C" void kernel_launch(void* const* d_in, const int* in_sizes, int n_in,
                              void* d_out, int out_size, void* d_ws, size_t ws_size,
                              hipStream_t stream) {
    const float* inputs = (const float*)d_in[0];
    const float* e_x    = (const float*)d_in[1];
    const float* e_h    = (const float*)d_in[2];
    const float* e_m    = (const float*)d_in[3];
    const float* W_x    = (const float*)d_in[4];
    const float* W_h    = (const float*)d_in[5];
    const float* W_m    = (const float*)d_in[6];
    const float* AT     = (const float*)d_in[7];
    const float* BT     = (const float*)d_in[8];
    const float* W_d    = (const float*)d_in[9];
    const float* b_d    = (const float*)d_in[10];
    (void)d_ws; (void)ws_size; (void)in_sizes; (void)n_in;

    prep_wmb<<<256, 256, 0, stream>>>(W_m, BT);
    prep_wma<<<dim3(16, 32), 256, 0, stream>>>(W_m, AT);
    prep_wfull<<<9216, 256, 0, stream>>>(W_h, AT, BT, e_h, e_m, e_x, W_x);

    lmu_persist<<<256, 256, 0, stream>>>(inputs);

    lmu_out<<<128, 256, 0, stream>>>(W_d, b_d, (float*)d_out);
}

// Round 18
// 3852.415 us; speedup vs baseline: 1.1722x; 1.0752x over previous
//
#include <hip/hip_runtime.h>
#include <hip/hip_fp16.h>
#include <cmath>

// ---------------------------------------------------------------------------
// LMU fused recurrence.  One 128x1536 @ 1536x1536 GEMM per step (tanh on
// first 1024 cols, linear on last 512), x-dependent rank-1 bias.
// r18 = r13 (best known good, 3.95 ms, replay-stable) + branch-free fast
// tanh (v_exp_f32-based, ~6 instr vs libm tanhf's ~35 w/ branches).
//   Barrier A/B history: flat single counter (r13, 3.95) beats parallel
//   sweep (r17, 4.14) and tree (r15, 4.52) -> the flat RMW counter is at
//   its minimal cost; the residual step time is the structural L2->CU state
//   fill (96 KB/CU/step) + compute at DVFS-depressed clock, not sync.
//   Locked-in lessons: barrier words touched by atomic RMWs ONLY (r16:
//   mixed store+RMW races; r12: InstCombine demotes fetch_add(0) to a load;
//   r14: even sc0 loads are served stale from L1).
// Design (= r13):
//   - XCD-local islands (s_getreg XCC_ID + rank registration, 1 WG/CU).
//   - Flat per-island arrival counter in the LOCAL XCD L2 (workgroup-scope
//     RMWs); poll = inline-asm global_atomic_add +0 sc0; busy spin.
//   - W_lo fully register-resident: 36 x half8 = 144 AGPRs/lane.
//   - W_hi slice (147 KB) in LDS; plain L2-local state loads/stores;
//     per-step CU-local L1 buffer_inv.
// Precision: EXACT r3-r13 verified scheme (absmax 4.9e-4): f16 hi/lo state
// and weights (lo x2048), fp32 MFMA accumulate, 3 products.
// ---------------------------------------------------------------------------

typedef _Float16 half8 __attribute__((ext_vector_type(8)));
typedef float floatx4 __attribute__((ext_vector_type(4)));

#define NSTATE   1536
#define BATCH    128
#define TSTEPS   784
#define KTILES   48
#define ISL_WGS  32                  // WGs per island (= CUs per XCD)
#define SLICE_H8 9216                // half8 per 48-col weight slice (48*3*64)
#define LO_SCALE 2048.0f
#define LO_INV   (1.0f / 2048.0f)

__device__ __align__(16) _Float16 g_Whi[NSTATE * NSTATE];
__device__ __align__(16) _Float16 g_Wlo[NSTATE * NSTATE];
__device__ float    g_wb[NSTATE];
__device__ float    g_WmA[1024 * 512];
__device__ float    g_WmB[1024];
__device__ __align__(16) _Float16 g_Shi[2 * BATCH * NSTATE];
__device__ __align__(16) _Float16 g_Slo[2 * BATCH * NSTATE];
// [xcd*64]: island arrival counters; [512 + xcd*64]: registration counters
__device__ unsigned g_bar[1024];

// Forced local-L2 atomic RMW poll (returns pre-add value).  InstCombine
// cannot demote this to a (stale-L1-cacheable) load -- r12/r14 lessons.
__device__ __forceinline__ unsigned poll_rmw(unsigned* p) {
    unsigned old;
    asm volatile("global_atomic_add %0, %1, %2, off sc0\n\ts_waitcnt vmcnt(0)"
                 : "=&v"(old)
                 : "v"(p), "v"(0u)
                 : "memory");
    return old;
}

// Branch-free tanh: 1 - 2/(e^{2x}+1).  __expf -> v_exp_f32.  Exact limits:
// e=inf -> 1, e=0 -> -1.  |err| ~1e-7 (absmax margin is 20x).
__device__ __forceinline__ float fast_tanh(float x) {
    float e = __expf(2.f * x);
    return 1.f - 2.f / (e + 1.f);
}

// W_mB[i] = sum_c W_m[i,c] * BT[c]
__global__ void prep_wmb(const float* __restrict__ Wm, const float* __restrict__ BT) {
    int row  = blockIdx.x * 4 + (threadIdx.x >> 6);
    int lane = threadIdx.x & 63;
    float s = 0.f;
    for (int c = lane; c < 512; c += 64) s += Wm[row * 512 + c] * BT[c];
    for (int o = 32; o; o >>= 1) s += __shfl_down(s, o);
    if (lane == 0) g_WmB[row] = s;
}

// W_mA = W_m @ (I + AT)
__global__ void prep_wma(const float* __restrict__ Wm, const float* __restrict__ AT) {
    __shared__ float As[32][33], Bs[32][33];
    int d0 = blockIdx.x * 32, i0 = blockIdx.y * 32;
    int tx = threadIdx.x & 31, ty = threadIdx.x >> 5;
    float acc[4];
#pragma unroll
    for (int r = 0; r < 4; ++r) acc[r] = Wm[(i0 + ty + 8 * r) * 512 + d0 + tx];
    for (int c0 = 0; c0 < 512; c0 += 32) {
#pragma unroll
        for (int r = 0; r < 4; ++r) {
            As[ty + 8 * r][tx] = Wm[(i0 + ty + 8 * r) * 512 + c0 + tx];
            Bs[ty + 8 * r][tx] = AT[(c0 + ty + 8 * r) * 512 + d0 + tx];
        }
        __syncthreads();
#pragma unroll
        for (int c = 0; c < 32; ++c)
#pragma unroll
            for (int r = 0; r < 4; ++r) acc[r] += As[ty + 8 * r][c] * Bs[c][tx];
        __syncthreads();
    }
#pragma unroll
    for (int r = 0; r < 4; ++r) g_WmA[(i0 + ty + 8 * r) * 512 + d0 + tx] = acc[r];
}

// Build W_full, f16 hi/lo (lo x2048), in slice-major fragment order:
// storage s = (((sl*48 + kt)*3 + nt)*64 + lane)*8 + j
//   n = sl*48 + nt*16 + (lane&15),  k = kt*32 + ((lane>>4)&3)*8 + j
__global__ void prep_wfull(const float* __restrict__ Wh, const float* __restrict__ AT,
                           const float* __restrict__ BT, const float* __restrict__ eh,
                           const float* __restrict__ em, const float* __restrict__ ex,
                           const float* __restrict__ Wx) {
    int s = blockIdx.x * 256 + threadIdx.x;     // [0, 1536*1536)
    int j8 = s & 7;
    int u = s >> 3;
    int lane = u & 63;
    u >>= 6;                                    // [0, 4608)
    int nt = u % 3; u /= 3;
    int kt = u % 48;
    int sl = u / 48;
    int n = sl * 48 + nt * 16 + (lane & 15);
    int k = kt * 32 + ((lane >> 4) & 3) * 8 + j8;

    float w;
    if (n < 1024) {
        if (k < 1024) w = Wh[n * 1024 + k] + g_WmB[n] * eh[k];
        else          w = g_WmA[n * 512 + (k - 1024)] + g_WmB[n] * em[k - 1024];
    } else {
        int c = n - 1024;
        if (k < 1024) w = BT[c] * eh[k];
        else {
            int d = k - 1024;
            w = ((c == d) ? 1.f : 0.f) + AT[c * 512 + d] + BT[c] * em[d];
        }
    }
    _Float16 hi = (_Float16)w;
    g_Whi[s] = hi;
    g_Wlo[s] = (_Float16)((w - (float)hi) * LO_SCALE);

    if (s < NSTATE) {
        float b = (s < 1024) ? (Wx[s] + ex[0] * g_WmB[s]) : (BT[s - 1024] * ex[0]);
        g_wb[s] = b;
    }
    if (s < 2 * BATCH * NSTATE) { g_Shi[s] = (_Float16)0.f; g_Slo[s] = (_Float16)0.f; }
    if (s < 1024) g_bar[s] = 0u;
}

__launch_bounds__(256, 1)
__global__ void lmu_persist(const float* __restrict__ inputs) {
    __shared__ half8  lwh[SLICE_H8];            // 147456 B: W_hi slice
    __shared__ float4 red[4 * 3 * 64];          // 12288 B: K-split partials
    __shared__ int    s_sl;

    const int tid = threadIdx.x;

    // ---- physical XCD id + rank registration (island = XCD) ----
    unsigned xcd;
    asm volatile("s_getreg_b32 %0, hwreg(HW_REG_XCC_ID)" : "=s"(xcd));
    xcd &= 7u;
    if (tid == 0) {
        unsigned rank = __hip_atomic_fetch_add(g_bar + 512 + xcd * 64, 1u,
                                               __ATOMIC_RELAXED,
                                               __HIP_MEMORY_SCOPE_WORKGROUP);
        s_sl = (int)(rank & 31u);               // column slice [0,32)
    }
    __syncthreads();
    const int isl = (int)xcd;                   // batch rows isl*16..+16
    const int sl  = s_sl;                       // cols sl*48..+48

    // stage W_hi slice -> LDS
    {
        const half8* src = (const half8*)g_Whi + (size_t)sl * SLICE_H8;
        for (int i = tid; i < SLICE_H8; i += 256) lwh[i] = src[i];
    }

    const int lane = tid & 63, wv = tid >> 6;
    const int quad = lane >> 4, l16 = lane & 15;
    const int kt0 = wv * 12;                    // this wave's K range
    const int rowA = isl * 16 + l16;            // A-frag batch row
    unsigned* cnt = g_bar + isl * 64;           // island arrival counter (local L2)

    // epilogue constants (wave wv<3 handles nt=wv)
    const int ncol = sl * 48 + wv * 16 + l16;
    const float wbv = (wv < 3) ? g_wb[ncol] : 0.f;
    const bool do_tanh = (sl * 48 + wv * 16) < 1024;

    // ---- W_lo: FULLY register-resident (36 x half8 = 144 AGPRs), loaded once
    half8 wr[12 * 3];
    {
        const half8* wlo = (const half8*)g_Wlo + (size_t)sl * SLICE_H8;
#pragma unroll
        for (int ki = 0; ki < 12; ++ki)
#pragma unroll
            for (int nt = 0; nt < 3; ++nt)
                wr[ki * 3 + nt] = wlo[((kt0 + ki) * 3 + nt) * 64 + lane];
    }

    __syncthreads();

    int buf = 0;
    for (int t = 0; t < TSTEPS; ++t) {
        // PLAIN loads: producers share this XCD's L2 -> L2-local traffic
        const _Float16* shr =
            g_Shi + buf * BATCH * NSTATE + rowA * NSTATE + quad * 8;
        const _Float16* slr =
            g_Slo + buf * BATCH * NSTATE + rowA * NSTATE + quad * 8;

        floatx4 aA[3], aB[3], aC[3];
#pragma unroll
        for (int q = 0; q < 3; ++q) { aA[q] = (floatx4)0.f; aB[q] = (floatx4)0.f; aC[q] = (floatx4)0.f; }

#pragma unroll
        for (int ki = 0; ki < 12; ++ki) {
            const int kt = kt0 + ki;
            half8 ah = *(const half8*)(shr + kt * 32);
            half8 al = *(const half8*)(slr + kt * 32);
#pragma unroll
            for (int nt = 0; nt < 3; ++nt) {
                half8 bh = lwh[(kt * 3 + nt) * 64 + lane];
                aA[nt] = __builtin_amdgcn_mfma_f32_16x16x32_f16(ah, bh, aA[nt], 0, 0, 0);
                aB[nt] = __builtin_amdgcn_mfma_f32_16x16x32_f16(al, bh, aB[nt], 0, 0, 0);
                aC[nt] = __builtin_amdgcn_mfma_f32_16x16x32_f16(ah, wr[ki * 3 + nt], aC[nt], 0, 0, 0);
            }
        }

        // K-split partials -> LDS
#pragma unroll
        for (int nt = 0; nt < 3; ++nt) {
            floatx4 P = aA[nt] + (aB[nt] + aC[nt]) * LO_INV;
            red[(wv * 3 + nt) * 64 + lane] = float4{P[0], P[1], P[2], P[3]};
        }
        __syncthreads();

        // waves 0-2: reduce + bias + activation + hi/lo split + PLAIN store
        const int nbuf = buf ^ 1;
        if (wv < 3) {
            float4 v0 = red[(0 * 3 + wv) * 64 + lane];
            float4 v1 = red[(1 * 3 + wv) * 64 + lane];
            float4 v2 = red[(2 * 3 + wv) * 64 + lane];
            float4 v3 = red[(3 * 3 + wv) * 64 + lane];
            float vr4[4] = {v0.x + v1.x + v2.x + v3.x, v0.y + v1.y + v2.y + v3.y,
                            v0.z + v1.z + v2.z + v3.z, v0.w + v1.w + v2.w + v3.w};
            _Float16* dh = g_Shi + nbuf * BATCH * NSTATE;
            _Float16* dl = g_Slo + nbuf * BATCH * NSTATE;
            const float* xt = inputs + t * BATCH + isl * 16 + quad * 4;
#pragma unroll
            for (int r = 0; r < 4; ++r) {
                int b = isl * 16 + quad * 4 + r;
                float v = vr4[r] + xt[r] * wbv;
                if (do_tanh) v = fast_tanh(v);
                _Float16 hi = (_Float16)v;
                dh[b * NSTATE + ncol] = hi;
                dl[b * NSTATE + ncol] = (_Float16)((v - (float)hi) * LO_SCALE);
            }
        }

        // drain stores (syncthreads emits vmcnt(0)), then flat LOCAL-L2
        // barrier: arrival = wg-scope RMW(+1); poll = asm RMW(+0) sc0.
        __builtin_amdgcn_fence(__ATOMIC_RELEASE, "workgroup");
        __syncthreads();
        if (tid == 0) {
            __hip_atomic_fetch_add(cnt, 1u, __ATOMIC_RELAXED,
                                   __HIP_MEMORY_SCOPE_WORKGROUP);
            const unsigned target = (unsigned)ISL_WGS * (unsigned)(t + 1);
            int spin = 0;
            while (poll_rmw(cnt) < target) {
                if (++spin > (1 << 18)) break;  // deadman: no hang
            }
        }
        __syncthreads();
        // CU-local L1 invalidate only (L2 holds the island's fresh state)
        asm volatile("buffer_inv\n\ts_waitcnt vmcnt(0)" ::: "memory");
        __builtin_amdgcn_fence(__ATOMIC_ACQUIRE, "workgroup");
        buf = nbuf;
    }
}

// logits + softmax: one WG per batch row (final state in plane 0: 784 even;
// dispatch boundary flushes every XCD's L2 so state is globally visible).
__global__ void lmu_out(const float* __restrict__ Wd, const float* __restrict__ bd,
                        float* __restrict__ out) {
    __shared__ float red[272];
    int b = blockIdx.x;
    const _Float16* sh = g_Shi + b * NSTATE;
    const _Float16* sl = g_Slo + b * NSTATE;
    int tid = threadIdx.x;
    int c = tid & 15, chunk = tid >> 4;
    float part = 0.f;
    if (c < 10) {
        for (int i = chunk * 64; i < chunk * 64 + 64; ++i)
            part += ((float)sh[i] + (float)sl[i] * LO_INV) * Wd[c * 1024 + i];
    }
    red[chunk * 16 + c] = part;
    __syncthreads();
    if (tid < 10) {
        float lg = bd[tid];
        for (int q = 0; q < 16; ++q) lg += red[q * 16 + tid];
        red[256 + tid] = lg;
    }
    __syncthreads();
    if (tid < 10) {
        float mx = red[256];
        for (int q = 1; q < 10; ++q) mx = fmaxf(mx, red[256 + q]);
        float sm = 0.f;
        for (int q = 0; q < 10; ++q) sm += expf(red[256 + q] - mx);
        out[b * 10 + tid] = expf(red[256 + tid] - mx) / sm;
    }
}

extern "C" void kernel_launch(void* const* d_in, const int* in_sizes, int n_in,
                              void* d_out, int out_size, void* d_ws, size_t ws_size,
                              hipStream_t stream) {
    const float* inputs = (const float*)d_in[0];
    const float* e_x    = (const float*)d_in[1];
    const float* e_h    = (const float*)d_in[2];
    const float* e_m    = (const float*)d_in[3];
    const float* W_x    = (const float*)d_in[4];
    const float* W_h    = (const float*)d_in[5];
    const float* W_m    = (const float*)d_in[6];
    const float* AT     = (const float*)d_in[7];
    const float* BT     = (const float*)d_in[8];
    const float* W_d    = (const float*)d_in[9];
    const float* b_d    = (const float*)d_in[10];
    (void)d_ws; (void)ws_size; (void)in_sizes; (void)n_in;

    prep_wmb<<<256, 256, 0, stream>>>(W_m, BT);
    prep_wma<<<dim3(16, 32), 256, 0, stream>>>(W_m, AT);
    prep_wfull<<<9216, 256, 0, stream>>>(W_h, AT, BT, e_h, e_m, e_x, W_x);

    lmu_persist<<<256, 256, 0, stream>>>(inputs);

    lmu_out<<<128, 256, 0, stream>>>(W_d, b_d, (float*)d_out);
}